// Round 13
// baseline (163.401 us; speedup 1.0000x reference)
//
#include <hip/hip_runtime.h>
#include <hip/hip_bf16.h>

#define NN 50000
#define FF 128
#define UU 128
#define NREL 8
#define NE 60000
#define NKEY (NREL * NN)        // 400000
#define NET (NREL * NE)         // 480000

typedef __attribute__((ext_vector_type(8))) short bf16x8;
typedef __attribute__((ext_vector_type(4))) float f32x4;

// ---------------- prep: X->bf16, W->fragment layout, head = -1 ----------------
// Wf layout: for (m,c,s), a 1KB block at ((m*8+c)*4+s)*512 ushorts; lane
// (ag*16+al) holds 8 bf16 of W_m[k = s*32+ag*8+j][col = c*16+al], j=0..7.

__global__ __launch_bounds__(256) void prep_kernel(
    const float* __restrict__ X, const float* __restrict__ Wself,
    const float* __restrict__ Wrel, ushort* __restrict__ Xb,
    ushort* __restrict__ Wf, int* __restrict__ head)
{
    int i = blockIdx.x * 256 + threadIdx.x;
    if (i < NN * FF / 4) {                      // X -> bf16
        float4 v = ((const float4*)X)[i];
        union { __hip_bfloat162 h[2]; uint2 u; } p;
        p.h[0] = __float22bfloat162_rn(make_float2(v.x, v.y));
        p.h[1] = __float22bfloat162_rn(make_float2(v.z, v.w));
        ((uint2*)Xb)[i] = p.u;
    }
    if (i < NKEY) head[i] = -1;
    if (i < 9 * FF * UU) {                      // W -> fragment layout
        int m = i >> 14, k = (i >> 7) & 127, col = i & 127;
        int c = col >> 4, al = col & 15;
        int s = k >> 5, ag = (k >> 3) & 3, j = k & 7;
        float v = (m == 0) ? Wself[i] : Wrel[i - FF * UU];
        __hip_bfloat16 h = __float2bfloat16(v);
        Wf[((m * 8 + c) * 4 + s) * 512 + (ag * 16 + al) * 8 + j] = *(ushort*)&h;
    }
}

// ---------------- per-(rel,dst) linked list with packed records ----------------

__global__ __launch_bounds__(256) void build_kernel(
    const int* __restrict__ esrc, const int* __restrict__ edst,
    const float* __restrict__ ew, int* __restrict__ head, int4* __restrict__ rec)
{
    int i = blockIdx.x * 256 + threadIdx.x;
    if (i < NET) {
        int key = (i / NE) * NN + edst[i];      // const divisor -> magic mul
        int prev = atomicExch(&head[key], i);
        rec[i] = make_int4(esrc[i], __float_as_int(ew[i]), prev, 0);
    }
}

// ---------------- pass 1: aggregation, one wave per 8 keys, LOCKSTEP walks ------
// Zb[key][0:128) = bf16( sum w * X[src] ); zeros if list empty. Lane l owns
// ushorts 2l, 2l+1. All 8 walks advance together: each iteration issues up to
// 8 independent X-gathers, then up to 8 advance steps (FMA + next-rec load),
// cutting the per-wave serial chain from sum(n_i) to max(n_i) latencies.
// All walk branches are wave-uniform (keys are per-wave).

#define AGG_DECL(i) int4 r##i = make_int4(0, 0, 0, 0); \
    float ax##i = 0.f, ay##i = 0.f;

#define AGG_ROOT(i) if (e##i >= 0) r##i = rec[e##i];

#define AGG_XL(i) uint x##i = 0u; \
    if (e##i >= 0) x##i = *(const uint*)(Xb + (size_t)r##i.x * FF + 2 * l);

#define AGG_ADV(i) if (e##i >= 0) { \
        float wgt = __int_as_float(r##i.y); \
        ax##i = fmaf(__uint_as_float(x##i << 16), wgt, ax##i); \
        ay##i = fmaf(__uint_as_float(x##i & 0xffff0000u), wgt, ay##i); \
        e##i = r##i.z; \
        if (e##i >= 0) r##i = rec[e##i]; \
    }

#define AGG_ST(i) { \
        __hip_bfloat162 hh = __float22bfloat162_rn(make_float2(ax##i, ay##i)); \
        *(uint*)(Zb + (size_t)(k0 + i) * FF + 2 * l) = *(uint*)&hh; }

__global__ __launch_bounds__(256) void agg_kernel(
    const ushort* __restrict__ Xb, const int* __restrict__ head,
    const int4* __restrict__ rec, ushort* __restrict__ Zb)
{
    const int k0 = ((blockIdx.x * 256 + threadIdx.x) >> 6) * 8;
    const int l = threadIdx.x & 63;

    const int4 h0 = *(const int4*)&head[k0];
    const int4 h1 = *(const int4*)&head[k0 + 4];
    int e0 = h0.x, e1 = h0.y, e2 = h0.z, e3 = h0.w;
    int e4 = h1.x, e5 = h1.y, e6 = h1.z, e7 = h1.w;

    AGG_DECL(0) AGG_DECL(1) AGG_DECL(2) AGG_DECL(3)
    AGG_DECL(4) AGG_DECL(5) AGG_DECL(6) AGG_DECL(7)

    AGG_ROOT(0) AGG_ROOT(1) AGG_ROOT(2) AGG_ROOT(3)
    AGG_ROOT(4) AGG_ROOT(5) AGG_ROOT(6) AGG_ROOT(7)

    while ((e0 >= 0) || (e1 >= 0) || (e2 >= 0) || (e3 >= 0) ||
           (e4 >= 0) || (e5 >= 0) || (e6 >= 0) || (e7 >= 0)) {
        AGG_XL(0) AGG_XL(1) AGG_XL(2) AGG_XL(3)
        AGG_XL(4) AGG_XL(5) AGG_XL(6) AGG_XL(7)
        AGG_ADV(0) AGG_ADV(1) AGG_ADV(2) AGG_ADV(3)
        AGG_ADV(4) AGG_ADV(5) AGG_ADV(6) AGG_ADV(7)
    }

    AGG_ST(0) AGG_ST(1) AGG_ST(2) AGG_ST(3)
    AGG_ST(4) AGG_ST(5) AGG_ST(6) AGG_ST(7)
}

// ---------------- pass 2: GEMM with LDS-staged W + A double-buffer ----------------
// Block = 4 waves, wave = one 16-row tile. Per m: W plane staged via regs into
// one 32KB LDS buffer (next plane prefetched into regs), A-frags for m+1
// loaded into the off-parity register set BEFORE m's MFMA burst -> HBM latency
// hides under MFMA + ds_read + barrier. Fully unrolled m-loop keeps aA/aB
// indices static (registers, no scratch). D: col=c*16+al, row=R0+ag*4+q.

#define LOAD_A(AF, P)                                                        \
    _Pragma("unroll")                                                        \
    for (int s = 0; s < 4; ++s)                                              \
        AF[s] = *(const bf16x8*)((P) + s * 32 + ag * 8);

#define MFMA_BURST(AF)                                                       \
    _Pragma("unroll")                                                        \
    for (int c = 0; c < 8; ++c) {                                            \
        _Pragma("unroll")                                                    \
        for (int s = 0; s < 4; ++s) {                                        \
            bf16x8 bfr = *(const bf16x8*)&bsh[(c * 4 + s) * 64 + l];         \
            acc[c] = __builtin_amdgcn_mfma_f32_16x16x32_bf16(                \
                AF[s], bfr, acc[c], 0, 0, 0);                                \
        }                                                                    \
    }

__global__ __launch_bounds__(256, 3) void gemm_kernel(
    const ushort* __restrict__ Xb, const ushort* __restrict__ Zb,
    const ushort* __restrict__ Wf, const float* __restrict__ bias,
    float* __restrict__ out)
{
    __shared__ uint4 bsh[2048];                 // 32 KB: one Wf plane
    const int t = threadIdx.x;
    const int wid = t >> 6;
    const int l = t & 63;
    const int gw0 = blockIdx.x * 4 + wid;
    const int gwid = (gw0 < NN / 16) ? gw0 : NN / 16 - 1;  // dup tail, benign
    const int R0 = gwid * 16;
    const int al = l & 15;
    const int ag = l >> 4;

    const uint4* Wf4 = (const uint4*)Wf;

    f32x4 acc[8];
    #pragma unroll
    for (int c = 0; c < 8; ++c) acc[c] = (f32x4){0.f, 0.f, 0.f, 0.f};

    // prologue: W[0] into stg regs, A[0] (Xb) into aA
    uint4 stg0 = Wf4[t +    0], stg1 = Wf4[t +  256];
    uint4 stg2 = Wf4[t +  512], stg3 = Wf4[t +  768];
    uint4 stg4 = Wf4[t + 1024], stg5 = Wf4[t + 1280];
    uint4 stg6 = Wf4[t + 1536], stg7 = Wf4[t + 1792];

    bf16x8 aA[4], aB[4];
    {
        const ushort* A0 = Xb + (size_t)(R0 + al) * FF;
        LOAD_A(aA, A0)
    }

    #pragma unroll
    for (int m = 0; m < 9; ++m) {
        __syncthreads();                        // prev MFMA done reading bsh
        bsh[t +    0] = stg0; bsh[t +  256] = stg1;
        bsh[t +  512] = stg2; bsh[t +  768] = stg3;
        bsh[t + 1024] = stg4; bsh[t + 1280] = stg5;
        bsh[t + 1536] = stg6; bsh[t + 1792] = stg7;
        if (m < 8) {                            // prefetch W[m+1]
            const uint4* Wn = Wf4 + (m + 1) * 2048;
            stg0 = Wn[t +    0]; stg1 = Wn[t +  256];
            stg2 = Wn[t +  512]; stg3 = Wn[t +  768];
            stg4 = Wn[t + 1024]; stg5 = Wn[t + 1280];
            stg6 = Wn[t + 1536]; stg7 = Wn[t + 1792];
        }
        if (m < 8) {                            // prefetch A[m+1] (Zb plane m)
            const ushort* An = Zb + ((size_t)m * NN + R0 + al) * FF;
            if ((m & 1) == 0) { LOAD_A(aB, An) } else { LOAD_A(aA, An) }
        }
        __syncthreads();                        // bsh writes visible
        if ((m & 1) == 0) { MFMA_BURST(aA) } else { MFMA_BURST(aB) }
    }

    #pragma unroll
    for (int c = 0; c < 8; ++c) {
        int col = c * 16 + al;
        float b = bias[col];
        #pragma unroll
        for (int q = 0; q < 4; ++q) {
            int row = R0 + ag * 4 + q;
            out[(size_t)row * UU + col] = fmaxf(acc[c][q] + b, 0.f);
        }
    }
}

// ---------------- launch ----------------

extern "C" void kernel_launch(void* const* d_in, const int* in_sizes, int n_in,
                              void* d_out, int out_size, void* d_ws, size_t ws_size,
                              hipStream_t stream) {
    const float* X     = (const float*)d_in[0];
    const int*   esrc  = (const int*)d_in[1];
    const int*   edst  = (const int*)d_in[2];
    const float* ew    = (const float*)d_in[3];
    const float* Wself = (const float*)d_in[4];
    const float* Wrel  = (const float*)d_in[5];
    const float* bias  = (const float*)d_in[6];
    float* out = (float*)d_out;

    // ws layout (16B-aligned segments), ~125 MB total
    ushort* Zb   = (ushort*)d_ws;               // NKEY*FF bf16 = 102.4 MB
    ushort* Xb   = Zb + (size_t)NKEY * FF;      // NN*FF bf16   = 12.8 MB
    ushort* Wf   = Xb + (size_t)NN * FF;        // 9*FF*UU bf16 = 0.29 MB
    int*    head = (int*)(Wf + 9 * FF * UU);    // NKEY         = 1.6 MB
    int4*   rec  = (int4*)(head + NKEY);        // NET int4     = 7.7 MB

    hipLaunchKernelGGL(prep_kernel,  dim3(NN * FF / 4 / 256), dim3(256), 0, stream,
                       X, Wself, Wrel, Xb, Wf, head);
    hipLaunchKernelGGL(build_kernel, dim3((NET + 255) / 256), dim3(256), 0, stream,
                       esrc, edst, ew, head, rec);
    hipLaunchKernelGGL(agg_kernel,   dim3(NKEY / 8 / 4), dim3(256), 0, stream,
                       Xb, head, rec, Zb);
    hipLaunchKernelGGL(gemm_kernel,  dim3((NN / 16 + 3) / 4), dim3(256), 0, stream,
                       Xb, Zb, Wf, bias, out);
}

// Round 14
// 126.947 us; speedup vs baseline: 1.2872x; 1.2872x over previous
//
#include <hip/hip_runtime.h>
#include <hip/hip_bf16.h>

#define NN 50000
#define FF 128
#define UU 128
#define NREL 8
#define NE 60000
#define NKEY (NREL * NN)        // 400000
#define NET (NREL * NE)         // 480000

typedef __attribute__((ext_vector_type(8))) short bf16x8;
typedef __attribute__((ext_vector_type(4))) float f32x4;

// ---------------- fused prep + build ----------------
// prep: X->bf16; W->fragment layout (for (m,c,s), a 1KB block at
// ((m*8+c)*4+s)*512 ushorts; lane (ag*16+al) holds 8 bf16 of
// W_m[k=s*32+ag*8+j][col=c*16+al]).
// build: per-(rel,dst) linked list via atomicExch (head pre-set to -1 by the
// stream-ordered memset); rec[i] = {src, w_bits, prev, pad}.

__global__ __launch_bounds__(256) void prepbuild_kernel(
    const float* __restrict__ X, const float* __restrict__ Wself,
    const float* __restrict__ Wrel, const int* __restrict__ esrc,
    const int* __restrict__ edst, const float* __restrict__ ew,
    ushort* __restrict__ Xb, ushort* __restrict__ Wf,
    int* __restrict__ head, int4* __restrict__ rec)
{
    int i = blockIdx.x * 256 + threadIdx.x;
    if (i < NN * FF / 4) {                      // X -> bf16
        float4 v = ((const float4*)X)[i];
        union { __hip_bfloat162 h[2]; uint2 u; } p;
        p.h[0] = __float22bfloat162_rn(make_float2(v.x, v.y));
        p.h[1] = __float22bfloat162_rn(make_float2(v.z, v.w));
        ((uint2*)Xb)[i] = p.u;
    }
    if (i < NET) {                              // linked-list build
        int key = (i / NE) * NN + edst[i];      // const divisor -> magic mul
        int prev = atomicExch(&head[key], i);
        rec[i] = make_int4(esrc[i], __float_as_int(ew[i]), prev, 0);
    }
    if (i < 9 * FF * UU) {                      // W -> fragment layout
        int m = i >> 14, k = (i >> 7) & 127, col = i & 127;
        int c = col >> 4, al = col & 15;
        int s = k >> 5, ag = (k >> 3) & 3, j = k & 7;
        float v = (m == 0) ? Wself[i] : Wrel[i - FF * UU];
        __hip_bfloat16 h = __float2bfloat16(v);
        Wf[((m * 8 + c) * 4 + s) * 512 + (ag * 16 + al) * 8 + j] = *(ushort*)&h;
    }
}

// ---------------- pass 1: aggregation, one wave per 4 consecutive keys ----------
// (round-12 structure, best measured) Zb[key][0:128) = bf16(sum w * X[src]);
// zeros if list empty. Lane l owns ushorts 2l, 2l+1. Heads (one int4) + root
// recs prefetched; each walk issues next-rec before its FMAs.

#define AGG_WALK(e, r, ax, ay)                                              \
    while (e >= 0) {                                                        \
        float w = __int_as_float(r.y);                                      \
        uint x = *(const uint*)(Xb + (size_t)r.x * FF + 2 * l);             \
        e = r.z;                                                            \
        if (e >= 0) r = rec[e];                                             \
        ax = fmaf(__uint_as_float(x << 16), w, ax);                         \
        ay = fmaf(__uint_as_float(x & 0xffff0000u), w, ay);                 \
    }

__global__ __launch_bounds__(256) void agg_kernel(
    const ushort* __restrict__ Xb, const int* __restrict__ head,
    const int4* __restrict__ rec, ushort* __restrict__ Zb)
{
    const int k0 = ((blockIdx.x * 256 + threadIdx.x) >> 6) * 4;
    const int l = threadIdx.x & 63;

    float a0x = 0.f, a0y = 0.f, a1x = 0.f, a1y = 0.f;
    float a2x = 0.f, a2y = 0.f, a3x = 0.f, a3y = 0.f;

    const int4 hv = *(const int4*)&head[k0];
    int e0 = hv.x, e1 = hv.y, e2 = hv.z, e3 = hv.w;
    int4 r0, r1, r2, r3;
    if (e0 >= 0) r0 = rec[e0];
    if (e1 >= 0) r1 = rec[e1];
    if (e2 >= 0) r2 = rec[e2];
    if (e3 >= 0) r3 = rec[e3];

    AGG_WALK(e0, r0, a0x, a0y)
    AGG_WALK(e1, r1, a1x, a1y)
    AGG_WALK(e2, r2, a2x, a2y)
    AGG_WALK(e3, r3, a3x, a3y)

    __hip_bfloat162 h;
    h = __float22bfloat162_rn(make_float2(a0x, a0y));
    *(uint*)(Zb + (size_t)(k0 + 0) * FF + 2 * l) = *(uint*)&h;
    h = __float22bfloat162_rn(make_float2(a1x, a1y));
    *(uint*)(Zb + (size_t)(k0 + 1) * FF + 2 * l) = *(uint*)&h;
    h = __float22bfloat162_rn(make_float2(a2x, a2y));
    *(uint*)(Zb + (size_t)(k0 + 2) * FF + 2 * l) = *(uint*)&h;
    h = __float22bfloat162_rn(make_float2(a3x, a3y));
    *(uint*)(Zb + (size_t)(k0 + 3) * FF + 2 * l) = *(uint*)&h;
}

// ---------------- pass 2: GEMM, W staged via global_load_lds + A dbuf ----------
// Block = 4 waves, wave = one 16-row tile. Per m: 8 global_load_lds_dwordx4
// per thread-slot pull the 32KB W plane straight into LDS (wave-uniform LDS
// base + per-lane global src — the supported linear pattern), A[m+1] reg
// loads issue in the same window, one drain at the barrier covers both.
// No stg regs, no ds_writes -> VGPR ~90, 4 waves/SIMD.
// D: col = c*16+al, row = R0 + ag*4 + q (layout verified rounds 5-13).

__device__ __forceinline__ void gload_lds16(const uint4* g, uint4* l) {
    __builtin_amdgcn_global_load_lds(
        (const __attribute__((address_space(1))) void*)g,
        (__attribute__((address_space(3))) void*)l, 16, 0, 0);
}

#define LOAD_A(AF, P)                                                        \
    _Pragma("unroll")                                                        \
    for (int s = 0; s < 4; ++s)                                              \
        AF[s] = *(const bf16x8*)((P) + s * 32 + ag * 8);

#define MFMA_BURST(AF)                                                       \
    _Pragma("unroll")                                                        \
    for (int c = 0; c < 8; ++c) {                                            \
        _Pragma("unroll")                                                    \
        for (int s = 0; s < 4; ++s) {                                        \
            bf16x8 bfr = *(const bf16x8*)&bsh[(c * 4 + s) * 64 + l];         \
            acc[c] = __builtin_amdgcn_mfma_f32_16x16x32_bf16(                \
                AF[s], bfr, acc[c], 0, 0, 0);                                \
        }                                                                    \
    }

__global__ __launch_bounds__(256, 4) void gemm_kernel(
    const ushort* __restrict__ Xb, const ushort* __restrict__ Zb,
    const ushort* __restrict__ Wf, const float* __restrict__ bias,
    float* __restrict__ out)
{
    __shared__ uint4 bsh[2048];                 // 32 KB: one Wf plane
    const int t = threadIdx.x;
    const int wid = t >> 6;
    const int l = t & 63;
    const int gw0 = blockIdx.x * 4 + wid;
    const int gwid = (gw0 < NN / 16) ? gw0 : NN / 16 - 1;  // dup tail, benign
    const int R0 = gwid * 16;
    const int al = l & 15;
    const int ag = l >> 4;

    const uint4* Wf4 = (const uint4*)Wf;

    f32x4 acc[8];
    #pragma unroll
    for (int c = 0; c < 8; ++c) acc[c] = (f32x4){0.f, 0.f, 0.f, 0.f};

    bf16x8 aA[4], aB[4];
    {
        const ushort* A0 = Xb + (size_t)(R0 + al) * FF;
        LOAD_A(aA, A0)
    }

    #pragma unroll
    for (int m = 0; m < 9; ++m) {
        __syncthreads();                        // prev MFMA done reading bsh
        {                                       // W[m] -> LDS via DMA
            const uint4* Wm = Wf4 + m * 2048 + wid * 64 + l;   // per-lane src
            uint4* lb = &bsh[wid * 64];                        // wave-uniform
            #pragma unroll
            for (int k = 0; k < 8; ++k)
                gload_lds16(Wm + k * 256, lb + k * 256);
        }
        if (m < 8) {                            // prefetch A[m+1] (Zb plane m)
            const ushort* An = Zb + ((size_t)m * NN + R0 + al) * FF;
            if ((m & 1) == 0) { LOAD_A(aB, An) } else { LOAD_A(aA, An) }
        }
        __syncthreads();                        // drains DMA + A loads
        if ((m & 1) == 0) { MFMA_BURST(aA) } else { MFMA_BURST(aB) }
    }

    #pragma unroll
    for (int c = 0; c < 8; ++c) {
        int col = c * 16 + al;
        float b = bias[col];
        #pragma unroll
        for (int q = 0; q < 4; ++q) {
            int row = R0 + ag * 4 + q;
            out[(size_t)row * UU + col] = fmaxf(acc[c][q] + b, 0.f);
        }
    }
}

// ---------------- launch ----------------

extern "C" void kernel_launch(void* const* d_in, const int* in_sizes, int n_in,
                              void* d_out, int out_size, void* d_ws, size_t ws_size,
                              hipStream_t stream) {
    const float* X     = (const float*)d_in[0];
    const int*   esrc  = (const int*)d_in[1];
    const int*   edst  = (const int*)d_in[2];
    const float* ew    = (const float*)d_in[3];
    const float* Wself = (const float*)d_in[4];
    const float* Wrel  = (const float*)d_in[5];
    const float* bias  = (const float*)d_in[6];
    float* out = (float*)d_out;

    // ws layout (16B-aligned segments), ~125 MB total
    ushort* Zb   = (ushort*)d_ws;               // NKEY*FF bf16 = 102.4 MB
    ushort* Xb   = Zb + (size_t)NKEY * FF;      // NN*FF bf16   = 12.8 MB
    ushort* Wf   = Xb + (size_t)NN * FF;        // 9*FF*UU bf16 = 0.29 MB
    int*    head = (int*)(Wf + 9 * FF * UU);    // NKEY         = 1.6 MB
    int4*   rec  = (int4*)(head + NKEY);        // NET int4     = 7.7 MB

    hipMemsetAsync(head, 0xFF, NKEY * sizeof(int), stream);   // head = -1
    hipLaunchKernelGGL(prepbuild_kernel, dim3(NN * FF / 4 / 256), dim3(256), 0, stream,
                       X, Wself, Wrel, esrc, edst, ew, Xb, Wf, head, rec);
    hipLaunchKernelGGL(agg_kernel,  dim3(NKEY / 16), dim3(256), 0, stream,
                       Xb, head, rec, Zb);
    hipLaunchKernelGGL(gemm_kernel, dim3((NN / 16 + 3) / 4), dim3(256), 0, stream,
                       Xb, Zb, Wf, bias, out);
}

// Round 15
// 123.630 us; speedup vs baseline: 1.3217x; 1.0268x over previous
//
#include <hip/hip_runtime.h>
#include <hip/hip_bf16.h>

#define NN 50000
#define FF 128
#define UU 128
#define NREL 8
#define NE 60000
#define NKEY (NREL * NN)        // 400000
#define NET (NREL * NE)         // 480000

typedef __attribute__((ext_vector_type(8))) short bf16x8;
typedef __attribute__((ext_vector_type(4))) float f32x4;

// ---------------- fused prep + build ----------------
// prep: X->bf16; W->fragment layout (for (m,c,s), a 1KB block at
// ((m*8+c)*4+s)*512 ushorts; lane (ag*16+al) holds 8 bf16 of
// W_m[k=s*32+ag*8+j][col=c*16+al]).
// build: per-(rel,dst) linked list via atomicExch (head pre-set to -1 by the
// stream-ordered memset); rec[i] = {src, w_bits, prev, pad}.

__global__ __launch_bounds__(256) void prepbuild_kernel(
    const float* __restrict__ X, const float* __restrict__ Wself,
    const float* __restrict__ Wrel, const int* __restrict__ esrc,
    const int* __restrict__ edst, const float* __restrict__ ew,
    ushort* __restrict__ Xb, ushort* __restrict__ Wf,
    int* __restrict__ head, int4* __restrict__ rec)
{
    int i = blockIdx.x * 256 + threadIdx.x;
    if (i < NN * FF / 4) {                      // X -> bf16
        float4 v = ((const float4*)X)[i];
        union { __hip_bfloat162 h[2]; uint2 u; } p;
        p.h[0] = __float22bfloat162_rn(make_float2(v.x, v.y));
        p.h[1] = __float22bfloat162_rn(make_float2(v.z, v.w));
        ((uint2*)Xb)[i] = p.u;
    }
    if (i < NET) {                              // linked-list build
        int key = (i / NE) * NN + edst[i];      // const divisor -> magic mul
        int prev = atomicExch(&head[key], i);
        rec[i] = make_int4(esrc[i], __float_as_int(ew[i]), prev, 0);
    }
    if (i < 9 * FF * UU) {                      // W -> fragment layout
        int m = i >> 14, k = (i >> 7) & 127, col = i & 127;
        int c = col >> 4, al = col & 15;
        int s = k >> 5, ag = (k >> 3) & 3, j = k & 7;
        float v = (m == 0) ? Wself[i] : Wrel[i - FF * UU];
        __hip_bfloat16 h = __float2bfloat16(v);
        Wf[((m * 8 + c) * 4 + s) * 512 + (ag * 16 + al) * 8 + j] = *(ushort*)&h;
    }
}

// ---------------- pass 1: aggregation, one wave per 4 consecutive keys ----------
// Zb[key][0:128) = bf16( sum w * X[src] ); zeros if list empty. Lane l owns
// ushorts 2l, 2l+1. First TWO list levels are unrolled and issued in parallel
// across all 4 walks (Poisson(1.2): 88% of keys have n<=2, so the serial tail
// loop is rare). All predicate conditions are wave-uniform.

#define AGG_L1R(i) int4 r##i = make_int4(0, 0, 0, 0); \
    if (e##i >= 0) r##i = rec[e##i];
#define AGG_L1X(i) uint x##i = 0u; \
    if (e##i >= 0) x##i = *(const uint*)(Xb + (size_t)r##i.x * FF + 2 * l);
#define AGG_L2R(i) int f##i = (e##i >= 0) ? r##i.z : -1; \
    int4 s##i = make_int4(0, 0, 0, 0); \
    if (f##i >= 0) s##i = rec[f##i];
#define AGG_L1A(i) if (e##i >= 0) { \
        float wgt = __int_as_float(r##i.y); \
        ax##i = fmaf(__uint_as_float(x##i << 16), wgt, ax##i); \
        ay##i = fmaf(__uint_as_float(x##i & 0xffff0000u), wgt, ay##i); }
#define AGG_L2X(i) uint y##i = 0u; \
    if (f##i >= 0) y##i = *(const uint*)(Xb + (size_t)s##i.x * FF + 2 * l);
#define AGG_L2A(i) if (f##i >= 0) { \
        float wgt = __int_as_float(s##i.y); \
        ax##i = fmaf(__uint_as_float(y##i << 16), wgt, ax##i); \
        ay##i = fmaf(__uint_as_float(y##i & 0xffff0000u), wgt, ay##i); \
        e##i = s##i.z; \
        if (e##i >= 0) r##i = rec[e##i]; \
    } else e##i = -1;

#define AGG_WALK(e, r, ax, ay)                                              \
    while (e >= 0) {                                                        \
        float w = __int_as_float(r.y);                                      \
        uint x = *(const uint*)(Xb + (size_t)r.x * FF + 2 * l);             \
        e = r.z;                                                            \
        if (e >= 0) r = rec[e];                                             \
        ax = fmaf(__uint_as_float(x << 16), w, ax);                         \
        ay = fmaf(__uint_as_float(x & 0xffff0000u), w, ay);                 \
    }

#define AGG_ST(i) { \
        __hip_bfloat162 hh = __float22bfloat162_rn(make_float2(ax##i, ay##i)); \
        *(uint*)(Zb + (size_t)(k0 + i) * FF + 2 * l) = *(uint*)&hh; }

__global__ __launch_bounds__(256) void agg_kernel(
    const ushort* __restrict__ Xb, const int* __restrict__ head,
    const int4* __restrict__ rec, ushort* __restrict__ Zb)
{
    const int k0 = ((blockIdx.x * 256 + threadIdx.x) >> 6) * 4;
    const int l = threadIdx.x & 63;

    float ax0 = 0.f, ay0 = 0.f, ax1 = 0.f, ay1 = 0.f;
    float ax2 = 0.f, ay2 = 0.f, ax3 = 0.f, ay3 = 0.f;

    const int4 hv = *(const int4*)&head[k0];
    int e0 = hv.x, e1 = hv.y, e2 = hv.z, e3 = hv.w;

    AGG_L1R(0) AGG_L1R(1) AGG_L1R(2) AGG_L1R(3)   // 4 root recs in flight
    AGG_L1X(0) AGG_L1X(1) AGG_L1X(2) AGG_L1X(3)   // 4 X-gathers in flight
    AGG_L2R(0) AGG_L2R(1) AGG_L2R(2) AGG_L2R(3)   // 4 level-2 recs (|| X)
    AGG_L1A(0) AGG_L1A(1) AGG_L1A(2) AGG_L1A(3)
    AGG_L2X(0) AGG_L2X(1) AGG_L2X(2) AGG_L2X(3)   // 4 level-2 X-gathers
    AGG_L2A(0) AGG_L2A(1) AGG_L2A(2) AGG_L2A(3)   // advance + tail prefetch

    AGG_WALK(e0, r0, ax0, ay0)                    // rare tails (n >= 3)
    AGG_WALK(e1, r1, ax1, ay1)
    AGG_WALK(e2, r2, ax2, ay2)
    AGG_WALK(e3, r3, ax3, ay3)

    AGG_ST(0) AGG_ST(1) AGG_ST(2) AGG_ST(3)
}

// ---------------- pass 2: GEMM, W staged via global_load_lds + A dbuf ----------
// Block = 4 waves, wave = one 16-row tile. Per m: 8 global_load_lds_dwordx4
// per thread-slot pull the 32KB W plane straight into LDS (wave-uniform LDS
// base + per-lane global src), A[m+1] reg loads issue in the same window,
// one drain at the barrier covers both. D: col=c*16+al, row=R0+ag*4+q.

__device__ __forceinline__ void gload_lds16(const uint4* g, uint4* l) {
    __builtin_amdgcn_global_load_lds(
        (const __attribute__((address_space(1))) void*)g,
        (__attribute__((address_space(3))) void*)l, 16, 0, 0);
}

#define LOAD_A(AF, P)                                                        \
    _Pragma("unroll")                                                        \
    for (int s = 0; s < 4; ++s)                                              \
        AF[s] = *(const bf16x8*)((P) + s * 32 + ag * 8);

#define MFMA_BURST(AF)                                                       \
    _Pragma("unroll")                                                        \
    for (int c = 0; c < 8; ++c) {                                            \
        _Pragma("unroll")                                                    \
        for (int s = 0; s < 4; ++s) {                                        \
            bf16x8 bfr = *(const bf16x8*)&bsh[(c * 4 + s) * 64 + l];         \
            acc[c] = __builtin_amdgcn_mfma_f32_16x16x32_bf16(                \
                AF[s], bfr, acc[c], 0, 0, 0);                                \
        }                                                                    \
    }

__global__ __launch_bounds__(256, 4) void gemm_kernel(
    const ushort* __restrict__ Xb, const ushort* __restrict__ Zb,
    const ushort* __restrict__ Wf, const float* __restrict__ bias,
    float* __restrict__ out)
{
    __shared__ uint4 bsh[2048];                 // 32 KB: one Wf plane
    const int t = threadIdx.x;
    const int wid = t >> 6;
    const int l = t & 63;
    const int gw0 = blockIdx.x * 4 + wid;
    const int gwid = (gw0 < NN / 16) ? gw0 : NN / 16 - 1;  // dup tail, benign
    const int R0 = gwid * 16;
    const int al = l & 15;
    const int ag = l >> 4;

    const uint4* Wf4 = (const uint4*)Wf;

    f32x4 acc[8];
    #pragma unroll
    for (int c = 0; c < 8; ++c) acc[c] = (f32x4){0.f, 0.f, 0.f, 0.f};

    bf16x8 aA[4], aB[4];
    {
        const ushort* A0 = Xb + (size_t)(R0 + al) * FF;
        LOAD_A(aA, A0)
    }

    #pragma unroll
    for (int m = 0; m < 9; ++m) {
        __syncthreads();                        // prev MFMA done reading bsh
        {                                       // W[m] -> LDS via DMA
            const uint4* Wm = Wf4 + m * 2048 + wid * 64 + l;   // per-lane src
            uint4* lb = &bsh[wid * 64];                        // wave-uniform
            #pragma unroll
            for (int k = 0; k < 8; ++k)
                gload_lds16(Wm + k * 256, lb + k * 256);
        }
        if (m < 8) {                            // prefetch A[m+1] (Zb plane m)
            const ushort* An = Zb + ((size_t)m * NN + R0 + al) * FF;
            if ((m & 1) == 0) { LOAD_A(aB, An) } else { LOAD_A(aA, An) }
        }
        __syncthreads();                        // drains DMA + A loads
        if ((m & 1) == 0) { MFMA_BURST(aA) } else { MFMA_BURST(aB) }
    }

    #pragma unroll
    for (int c = 0; c < 8; ++c) {
        int col = c * 16 + al;
        float b = bias[col];
        #pragma unroll
        for (int q = 0; q < 4; ++q) {
            int row = R0 + ag * 4 + q;
            out[(size_t)row * UU + col] = fmaxf(acc[c][q] + b, 0.f);
        }
    }
}

// ---------------- launch ----------------

extern "C" void kernel_launch(void* const* d_in, const int* in_sizes, int n_in,
                              void* d_out, int out_size, void* d_ws, size_t ws_size,
                              hipStream_t stream) {
    const float* X     = (const float*)d_in[0];
    const int*   esrc  = (const int*)d_in[1];
    const int*   edst  = (const int*)d_in[2];
    const float* ew    = (const float*)d_in[3];
    const float* Wself = (const float*)d_in[4];
    const float* Wrel  = (const float*)d_in[5];
    const float* bias  = (const float*)d_in[6];
    float* out = (float*)d_out;

    // ws layout (16B-aligned segments), ~125 MB total
    ushort* Zb   = (ushort*)d_ws;               // NKEY*FF bf16 = 102.4 MB
    ushort* Xb   = Zb + (size_t)NKEY * FF;      // NN*FF bf16   = 12.8 MB
    ushort* Wf   = Xb + (size_t)NN * FF;        // 9*FF*UU bf16 = 0.29 MB
    int*    head = (int*)(Wf + 9 * FF * UU);    // NKEY         = 1.6 MB
    int4*   rec  = (int4*)(head + NKEY);        // NET int4     = 7.7 MB

    hipMemsetAsync(head, 0xFF, NKEY * sizeof(int), stream);   // head = -1
    hipLaunchKernelGGL(prepbuild_kernel, dim3(NN * FF / 4 / 256), dim3(256), 0, stream,
                       X, Wself, Wrel, esrc, edst, ew, Xb, Wf, head, rec);
    hipLaunchKernelGGL(agg_kernel,  dim3(NKEY / 16), dim3(256), 0, stream,
                       Xb, head, rec, Zb);
    hipLaunchKernelGGL(gemm_kernel, dim3((NN / 16 + 3) / 4), dim3(256), 0, stream,
                       Xb, Zb, Wf, bias, out);
}